// Round 4
// baseline (1075.271 us; speedup 1.0000x reference)
//
#include <hip/hip_runtime.h>
#include <math.h>

// Problem constants (from reference)
#define N_NODES   100000
#define N_EDGES   1600000
#define NUM_RBF   128
#define NUM_GAUSS 32
#define NFEAT     160      // 128 + 32 -> 40 float4 columns per edge
#define CUTOFF    6.0f

#define COLS   40                         // float4 columns per edge
#define BLOCK  256                        // 4 waves, fill-like
#define GRID   2080                       // 2080*256 = 532480 threads (multiple of 40)
#define STRIDE (GRID * BLOCK)             // 532480 float4-columns per sweep
#define ESTRIDE (STRIDE / COLS)           // 13312 edges per sweep

static __device__ __forceinline__ float fast_exp2(float x) {
#if __has_builtin(__builtin_amdgcn_exp2f)
    return __builtin_amdgcn_exp2f(x);   // raw v_exp_f32 (D = 2^S0)
#else
    return __expf(0.6931471805599453f * x);
#endif
}

// Maximally "fill-like" writer: no LDS, no barriers, no divergent writer wave.
// Each thread owns one fixed float4 column (STRIDE is a multiple of 40), and
// grid-strides over edges. Per-edge scalars are recomputed redundantly by the
// ~40 threads sharing an edge (costs ~30us of VALU device-wide; gathers are
// L1/L2 broadcast hits). Stores: consecutive lanes -> consecutive 16B -> 1KiB
// per wave-instruction, 4 independent chains in flight per wave via unroll.
__global__ __launch_bounds__(BLOCK) void edge_feat_kernel(
    const float* __restrict__ pos,     // [N_NODES, 3]
    const int*   __restrict__ eidx,    // [2, N_EDGES]
    float*       __restrict__ out)     // [N_EDGES, 160]
{
    const int g0  = blockIdx.x * BLOCK + threadIdx.x;   // global float4-column id
    const int col = g0 % COLS;                          // fixed per thread
    const bool isRBF = (col < NUM_RBF / 4);

    // Reference constants (double-folded)
    const float start = (float)0.0024787521766663585;            // exp(-6)
    const float mstep = (float)((1.0 - 0.0024787521766663585) / (NUM_RBF - 1));
    const float beta  = (float)(1.0 /
        ((2.0 / NUM_RBF * (1.0 - 0.0024787521766663585)) *
         (2.0 / NUM_RBF * (1.0 - 0.0024787521766663585))));      // ~4116.4
    const float gstep = (float)(10.0 / (NUM_GAUSS - 1));
    const float ginv  = 20.48f;                                   // 1/(2*w^2)
    const float LOG2E = 1.4426950408889634f;

    const int f0 = col * 4;
    float4 C;
    float SB;
    if (isRBF) {
        C.x = start + (float)(f0 + 0) * mstep;
        C.y = start + (float)(f0 + 1) * mstep;
        C.z = start + (float)(f0 + 2) * mstep;
        C.w = start + (float)(f0 + 3) * mstep;
        SB  = sqrtf(beta * LOG2E);
    } else {
        const int g0f = f0 - NUM_RBF;
        C.x = (float)(g0f + 0) * gstep;
        C.y = (float)(g0f + 1) * gstep;
        C.z = (float)(g0f + 2) * gstep;
        C.w = (float)(g0f + 3) * gstep;
        SB  = sqrtf(ginv * LOG2E);
    }

    const size_t NF4 = (size_t)N_EDGES * COLS;   // 64,000,000 float4 columns
    float4* out4 = (float4*)out;

    int e = g0 / COLS;
    #pragma unroll 4
    for (size_t g = (size_t)g0; g < NF4; g += STRIDE, e += ESTRIDE) {
        // Gather (L1/L2 broadcast across the ~40 lanes sharing this edge)
        const int s = eidx[e];
        const int t = eidx[N_EDGES + e];
        const float dx = pos[3*s + 0] - pos[3*t + 0];
        const float dy = pos[3*s + 1] - pos[3*t + 1];
        const float dz = pos[3*s + 2] - pos[3*t + 2];
        const float dist = sqrtf(dx*dx + dy*dy + dz*dz + 1e-12f);
        const float cth = 0.5f * (__cosf(dist * (float)(M_PI / 6.0)) + 1.0f);
        const float cc = (dist < CUTOFF) ? cth : 0.0f;
        const float te = __expf(-(5.0f / 6.0f) * dist);

        const float X = isRBF ? te : dist;     // exp(-alpha*d) or d
        const float A = isRBF ? cc : 1.0f;     // cutoff or 1

        float4 r;
        {
            const float vx = (X - C.x) * SB;
            const float vy = (X - C.y) * SB;
            const float vz = (X - C.z) * SB;
            const float vw = (X - C.w) * SB;
            r.x = A * fast_exp2(-vx * vx);
            r.y = A * fast_exp2(-vy * vy);
            r.z = A * fast_exp2(-vz * vz);
            r.w = A * fast_exp2(-vw * vw);
        }
        out4[g] = r;
    }
}

extern "C" void kernel_launch(void* const* d_in, const int* in_sizes, int n_in,
                              void* d_out, int out_size, void* d_ws, size_t ws_size,
                              hipStream_t stream) {
    const float* pos  = (const float*)d_in[0];
    const int*   eidx = (const int*)d_in[1];
    float*       out  = (float*)d_out;

    edge_feat_kernel<<<GRID, BLOCK, 0, stream>>>(pos, eidx, out);
}

// Round 5
// 1001.002 us; speedup vs baseline: 1.0742x; 1.0742x over previous
//
#include <hip/hip_runtime.h>
#include <math.h>

// Problem constants (from reference)
#define N_NODES   100000
#define N_EDGES   1600000
#define NUM_RBF   128
#define NUM_GAUSS 32
#define NFEAT     160      // 128 + 32 -> 40 float4 columns per edge
#define CUTOFF    6.0f

#define EPB    64          // edges per block
#define BLOCK  320         // 5 waves; 320/40 = 8 edges processed per iteration
#define COLS   40          // float4 columns per edge
#define EPI    (BLOCK/COLS) // 8 edges per iteration
#define NITER  (EPB/EPI)    // 8 iterations

static __device__ __forceinline__ float fast_exp2(float x) {
#if __has_builtin(__builtin_amdgcn_exp2f)
    return __builtin_amdgcn_exp2f(x);   // raw v_exp_f32 (D = 2^S0)
#else
    return __expf(0.6931471805599453f * x);
#endif
}

// Round-0 structure (best measured: 988us) with ONE change: the inner loop is
// split into compute-all-8 then burst-store-all-8, so each wave issues 8
// back-to-back 1KiB stores (fill-like outstanding-store depth) instead of
// interleaving each store with LDS reads + VALU + transcendentals.
__global__ __launch_bounds__(BLOCK) void edge_feat_kernel(
    const float* __restrict__ pos,     // [N_NODES, 3]
    const int*   __restrict__ eidx,    // [2, N_EDGES]
    float*       __restrict__ out)     // [N_EDGES, 160]
{
    __shared__ float4 s_edge[EPB];     // (dist, cutoff, exp(-alpha*d), 0)

    const int blockEdge0 = blockIdx.x * EPB;
    const int tid = threadIdx.x;

    // ---- Phase 1: per-edge scalars (threads 0..63) ----
    if (tid < EPB) {
        const int e = blockEdge0 + tid;
        const int s = eidx[e];
        const int t = eidx[N_EDGES + e];
        const float dx = pos[3*s + 0] - pos[3*t + 0];
        const float dy = pos[3*s + 1] - pos[3*t + 1];
        const float dz = pos[3*s + 2] - pos[3*t + 2];
        const float dist = sqrtf(dx*dx + dy*dy + dz*dz + 1e-12f);
        const float c = 0.5f * (__cosf(dist * (float)(M_PI / 6.0)) + 1.0f);
        const float cc = (dist < CUTOFF) ? c : 0.0f;
        const float te = __expf(-(5.0f / 6.0f) * dist);
        s_edge[tid] = make_float4(dist, cc, te, 0.0f);
    }
    __syncthreads();

    // ---- Per-thread loop-invariant constants (fixed feature column) ----
    const int col   = tid % COLS;       // float4 column 0..39
    const int eiter = tid / COLS;       // edge slot within an iteration 0..7
    const bool isRBF = (col < NUM_RBF / 4);

    // Reference constants (double-folded)
    const float start = (float)0.0024787521766663585;            // exp(-6)
    const float mstep = (float)((1.0 - 0.0024787521766663585) / (NUM_RBF - 1));
    const float beta  = (float)(1.0 /
        ((2.0 / NUM_RBF * (1.0 - 0.0024787521766663585)) *
         (2.0 / NUM_RBF * (1.0 - 0.0024787521766663585))));      // ~4116.4
    const float gstep = (float)(10.0 / (NUM_GAUSS - 1));
    const float ginv  = 20.48f;                                   // 1/(2*w^2)
    const float LOG2E = 1.4426950408889634f;

    // Centers for this thread's 4 features + sqrt(B*log2e) scale
    const int f0 = col * 4;
    float4 C;
    float SB;
    if (isRBF) {
        C.x = start + (float)(f0 + 0) * mstep;
        C.y = start + (float)(f0 + 1) * mstep;
        C.z = start + (float)(f0 + 2) * mstep;
        C.w = start + (float)(f0 + 3) * mstep;
        SB  = sqrtf(beta * LOG2E);
    } else {
        const int g0 = f0 - NUM_RBF;
        C.x = (float)(g0 + 0) * gstep;
        C.y = (float)(g0 + 1) * gstep;
        C.z = (float)(g0 + 2) * gstep;
        C.w = (float)(g0 + 3) * gstep;
        SB  = sqrtf(ginv * LOG2E);
    }

    // ---- Phase 2a: compute all 8 results into registers ----
    float4 rr[NITER];
    #pragma unroll
    for (int k = 0; k < NITER; ++k) {
        const float4 es = s_edge[k * EPI + eiter];  // LDS broadcast read
        const float X = isRBF ? es.z : es.x;        // exp(-alpha*d) or d
        const float A = isRBF ? es.y : 1.0f;        // cutoff or 1
        const float vx = (X - C.x) * SB;
        const float vy = (X - C.y) * SB;
        const float vz = (X - C.z) * SB;
        const float vw = (X - C.w) * SB;
        rr[k].x = A * fast_exp2(-vx * vx);
        rr[k].y = A * fast_exp2(-vy * vy);
        rr[k].z = A * fast_exp2(-vz * vz);
        rr[k].w = A * fast_exp2(-vw * vw);
    }

    // ---- Phase 2b: burst-store all 8 (back-to-back dwordx4, max vmcnt depth)
    float4* out4 = (float4*)(out + (size_t)blockEdge0 * NFEAT);
    #pragma unroll
    for (int k = 0; k < NITER; ++k) {
        out4[k * BLOCK + tid] = rr[k];
    }
}

extern "C" void kernel_launch(void* const* d_in, const int* in_sizes, int n_in,
                              void* d_out, int out_size, void* d_ws, size_t ws_size,
                              hipStream_t stream) {
    const float* pos  = (const float*)d_in[0];
    const int*   eidx = (const int*)d_in[1];
    float*       out  = (float*)d_out;

    const int nblocks = N_EDGES / EPB;   // 25,000
    edge_feat_kernel<<<nblocks, BLOCK, 0, stream>>>(pos, eidx, out);
}